// Round 3
// baseline (55.574 us; speedup 1.0000x reference)
//
#include <hip/hip_runtime.h>
#include <hip/hip_bf16.h>

typedef float  f32x4  __attribute__((ext_vector_type(4)));
typedef float  f32x16 __attribute__((ext_vector_type(16)));
typedef int    i32x4  __attribute__((ext_vector_type(4)));
typedef __bf16 bf16x8 __attribute__((ext_vector_type(8)));

#define LL 256   // h*w
#define NF 32    // hidden dim
#define NCH 64   // channels

// pack two f32 -> one u32 of 2 bf16 (RNE; compiler emits v_cvt_pk_bf16_f32)
__device__ __forceinline__ unsigned pack2(float lo, float hi) {
    unsigned short a = __builtin_bit_cast(unsigned short, (__bf16)lo);
    unsigned short b = __builtin_bit_cast(unsigned short, (__bf16)hi);
    return (unsigned)a | ((unsigned)b << 16);
}

__device__ __forceinline__ bf16x8 words_to_frag(unsigned w0, unsigned w1, unsigned w2, unsigned w3) {
    i32x4 w;
    w.x = (int)w0; w.y = (int)w1; w.z = (int)w2; w.w = (int)w3;
    return __builtin_bit_cast(bf16x8, w);
}

// ---------------- phase 0: A'[b,l,k] = o @ W0[:64] + b0 ; B[b,l,k] = o @ W0[64:] ----------------
__global__ __launch_bounds__(256) void rn_pre(
    const float* __restrict__ x, const float* __restrict__ W0,
    const float* __restrict__ b0, float* __restrict__ Ap, float* __restrict__ Bp)
{
    int gid = blockIdx.x * 256 + threadIdx.x;   // 32*256*32 = 262144 threads
    int k  = gid & 31;
    int bl = gid >> 5;          // b*256 + l
    int b  = bl >> 8;
    int l  = bl & 255;
    const float* xrow = x + b * NCH * LL + l;   // x[b][ch][l]
    float accA = 0.f, accB = 0.f;
    #pragma unroll 8
    for (int ch = 0; ch < NCH; ++ch) {
        float xv = xrow[ch * LL];
        accA += xv * W0[ch * NF + k];
        accB += xv * W0[(NCH + ch) * NF + k];
    }
    Ap[gid] = accA + b0[k];
    Bp[gid] = accB;
}

// ---------------- phase 1: fused pair loop ----------------
// grid: 32 batches x 64 pgroups = 2048 blocks, 256 threads (4 waves); wave owns ONE p.
// Feature permutation phi (4-blocks 1<->2, 5<->6, i.e. k^12) is folded into the W2
// A-fragment load so layer-1 C/D registers feed layer-2 B-operand with NO cross-lane ops.
__global__ __launch_bounds__(256) void rn_main(
    const float* __restrict__ Ap, const float* __restrict__ Bp,
    const float* __restrict__ W1, const float* __restrict__ b1,
    const float* __restrict__ W2, const float* __restrict__ b2,
    float* __restrict__ partials)
{
    const int tid  = threadIdx.x;
    const int lane = tid & 63;
    const int w    = tid >> 6;
    const int col  = lane & 31;     // MFMA column index
    const int hi   = lane >> 5;     // half-wave
    const int batch  = blockIdx.x >> 6;
    const int pgroup = blockIdx.x & 63;
    const int p      = pgroup * 4 + w;

    // ---- constant A-operand fragments ----
    // A1 slot(kh,hi,e) = W1[k][col], k = 16kh+8hi+e
    // A2 slot(kh,hi,e) = W2[phi(k)][col]
    bf16x8 a1[2], a2[2];
    #pragma unroll
    for (int kh = 0; kh < 2; ++kh) {
        unsigned w1w[4], w2w[4];
        #pragma unroll
        for (int j = 0; j < 4; ++j) {
            int k0 = kh * 16 + 8 * hi + 2 * j;
            int bk = (k0 >> 2) & 3;
            int fk = (bk == 1 || bk == 2) ? (k0 ^ 12) : k0;   // phi; phi(k0+1)=phi(k0)+1
            w1w[j] = pack2(W1[k0 * NF + col], W1[(k0 + 1) * NF + col]);
            w2w[j] = pack2(W2[fk * NF + col], W2[(fk + 1) * NF + col]);
        }
        a1[kh] = words_to_frag(w1w[0], w1w[1], w1w[2], w1w[3]);
        a2[kh] = words_to_frag(w2w[0], w2w[1], w2w[2], w2w[3]);
    }

    // ---- biases pre-arranged in the C/D register layout: row = (r&3)+8*(r>>2)+4*hi ----
    f32x16 bias1, bias2, sacc;
    #pragma unroll
    for (int r = 0; r < 16; ++r) {
        int row = (r & 3) + 8 * (r >> 2) + 4 * hi;
        bias1[r] = b1[row];
        bias2[r] = b2[row];
        sacc[r]  = 0.f;
    }

    // ---- B[p] slots for this wave (loaded once): bq[kh][h] = B[p][16kh+8hi+4h .. +3] ----
    const float* Brow = Bp + batch * LL * NF + p * NF + 8 * hi;
    f32x4 b00 = *(const f32x4*)(Brow);
    f32x4 b01 = *(const f32x4*)(Brow + 4);
    f32x4 b10 = *(const f32x4*)(Brow + 16);
    f32x4 b11 = *(const f32x4*)(Brow + 20);

    const float* Abase = Ap + batch * LL * NF + 8 * hi;

    #pragma unroll 2
    for (int q0 = 0; q0 < LL; q0 += 32) {
        const float* Arow = Abase + (q0 + col) * NF;
        f32x4 t00 = *(const f32x4*)(Arow);
        f32x4 t01 = *(const f32x4*)(Arow + 4);
        f32x4 t10 = *(const f32x4*)(Arow + 16);
        f32x4 t11 = *(const f32x4*)(Arow + 20);

        // h1 = relu(A'[q] + B[p]) -> bf16 B1-operand fragments (vector VALU)
        f32x4 z4 = (f32x4)0.0f;
        f32x4 s00 = __builtin_elementwise_max(t00 + b00, z4);
        f32x4 s01 = __builtin_elementwise_max(t01 + b01, z4);
        f32x4 s10 = __builtin_elementwise_max(t10 + b10, z4);
        f32x4 s11 = __builtin_elementwise_max(t11 + b11, z4);
        bf16x8 hf0 = words_to_frag(pack2(s00.x, s00.y), pack2(s00.z, s00.w),
                                   pack2(s01.x, s01.y), pack2(s01.z, s01.w));
        bf16x8 hf1 = words_to_frag(pack2(s10.x, s10.y), pack2(s10.z, s10.w),
                                   pack2(s11.x, s11.y), pack2(s11.z, s11.w));

        // layer 1: h2pre^T = W1^T . h1^T + b1 (bias as C-input, no copy)
        f32x16 acc1 = __builtin_amdgcn_mfma_f32_32x32x16_bf16(a1[0], hf0, bias1, 0, 0, 0);
        acc1        = __builtin_amdgcn_mfma_f32_32x32x16_bf16(a1[1], hf1, acc1, 0, 0, 0);

        // relu + pack; with phi folded into A2, register order IS the B2 slot order
        f32x16 r1 = __builtin_elementwise_max(acc1, (f32x16)0.0f);
        bf16x8 h2f0 = words_to_frag(pack2(r1[0],  r1[1]),  pack2(r1[2],  r1[3]),
                                    pack2(r1[4],  r1[5]),  pack2(r1[6],  r1[7]));
        bf16x8 h2f1 = words_to_frag(pack2(r1[8],  r1[9]),  pack2(r1[10], r1[11]),
                                    pack2(r1[12], r1[13]), pack2(r1[14], r1[15]));

        // layer 2: h3pre^T = W2~^T . h2~^T + b2
        f32x16 acc2 = __builtin_amdgcn_mfma_f32_32x32x16_bf16(a2[0], h2f0, bias2, 0, 0, 0);
        acc2        = __builtin_amdgcn_mfma_f32_32x32x16_bf16(a2[1], h2f1, acc2, 0, 0, 0);

        // accumulate relu(h3)
        sacc += __builtin_elementwise_max(acc2, (f32x16)0.0f);
    }

    // ---- reduce: sum over pair-columns (lanes within each 32-half), then over waves ----
    float red[16];
    #pragma unroll
    for (int r = 0; r < 16; ++r) {
        float v = sacc[r];
        #pragma unroll
        for (int m = 1; m < 32; m <<= 1) v += __shfl_xor(v, m, 32);
        red[r] = v;
    }
    __shared__ float smem[4][32];
    if (col == 0) {
        #pragma unroll
        for (int r = 0; r < 16; ++r)
            smem[w][(r & 3) + 8 * (r >> 2) + 4 * hi] = red[r];
    }
    __syncthreads();
    if (tid < 32) {
        float s = smem[0][tid] + smem[1][tid] + smem[2][tid] + smem[3][tid];
        partials[blockIdx.x * 32 + tid] = s;
    }
}

// ---------------- phase 2: reduce partials + MLP head ----------------
__global__ __launch_bounds__(1024) void rn_post(
    const float* __restrict__ partials,
    const float* __restrict__ Wp, const float* __restrict__ bp,
    const float* __restrict__ Wo, const float* __restrict__ bo,
    float* __restrict__ out)
{
    __shared__ float s_lds[32][32];
    __shared__ float f_lds[32][32];
    int tid = threadIdx.x;
    int b = tid >> 5, n = tid & 31;
    float s = 0.f;
    #pragma unroll 8
    for (int pb = 0; pb < 64; ++pb) s += partials[(b * 64 + pb) * 32 + n];
    s_lds[b][n] = s;
    __syncthreads();
    float f = bp[n];
    #pragma unroll
    for (int k = 0; k < 32; ++k) f += s_lds[b][k] * Wp[k * 32 + n];
    f_lds[b][n] = fmaxf(f, 0.f);
    __syncthreads();
    float o = bo[n];
    #pragma unroll
    for (int k = 0; k < 32; ++k) o += f_lds[b][k] * Wo[k * 32 + n];
    out[tid] = o;
}

extern "C" void kernel_launch(void* const* d_in, const int* in_sizes, int n_in,
                              void* d_out, int out_size, void* d_ws, size_t ws_size,
                              hipStream_t stream)
{
    const float* x  = (const float*)d_in[0];
    const float* W0 = (const float*)d_in[1];
    const float* b0 = (const float*)d_in[2];
    const float* W1 = (const float*)d_in[3];
    const float* b1 = (const float*)d_in[4];
    const float* W2 = (const float*)d_in[5];
    const float* b2 = (const float*)d_in[6];
    const float* Wp = (const float*)d_in[7];
    const float* bp = (const float*)d_in[8];
    const float* Wo = (const float*)d_in[9];
    const float* bo = (const float*)d_in[10];
    float* out = (float*)d_out;

    float* Ap       = (float*)d_ws;            // 32*256*32 = 262144 f32
    float* Bp       = Ap + 32 * LL * NF;       // 262144 f32
    float* partials = Bp + 32 * LL * NF;       // 2048*32 = 65536 f32

    rn_pre <<<1024, 256, 0, stream>>>(x, W0, b0, Ap, Bp);
    rn_main<<<2048, 256, 0, stream>>>(Ap, Bp, W1, b1, W2, b2, partials);
    rn_post<<<1, 1024, 0, stream>>>(partials, Wp, bp, Wo, bo, out);
}

// Round 5
// 39.490 us; speedup vs baseline: 1.4073x; 1.4073x over previous
//
#include <hip/hip_runtime.h>
#include <hip/hip_bf16.h>

typedef float    f32x4  __attribute__((ext_vector_type(4)));
typedef float    f32x16 __attribute__((ext_vector_type(16)));
typedef int      i32x4  __attribute__((ext_vector_type(4)));
typedef _Float16 f16x8  __attribute__((ext_vector_type(8)));

#define LL 256   // h*w
#define NF 32    // hidden dim
#define NCH 64   // channels

// HW pack: two f32 -> u32 of two fp16 (v_cvt_pkrtz_f16_f32)
__device__ __forceinline__ unsigned pkrtz(float lo, float hi) {
    return __builtin_bit_cast(unsigned, __builtin_amdgcn_cvt_pkrtz(lo, hi));
}

__device__ __forceinline__ f16x8 words_to_frag(unsigned w0, unsigned w1, unsigned w2, unsigned w3) {
    i32x4 w;
    w.x = (int)w0; w.y = (int)w1; w.z = (int)w2; w.w = (int)w3;
    return __builtin_bit_cast(f16x8, w);
}

// ---------------- phase 0: A'[b,l,k] = o @ W0[:64] + b0 (fp16) ; B[b,l,k] = o @ W0[64:] (fp16) ----
__global__ __launch_bounds__(256) void rn_pre(
    const float* __restrict__ x, const float* __restrict__ W0,
    const float* __restrict__ b0, _Float16* __restrict__ Ap, _Float16* __restrict__ Bp)
{
    int gid = blockIdx.x * 256 + threadIdx.x;   // 32*256*32 = 262144 threads
    int k  = gid & 31;
    int bl = gid >> 5;          // b*256 + l
    int b  = bl >> 8;
    int l  = bl & 255;
    const float* xrow = x + b * NCH * LL + l;   // x[b][ch][l]
    float accA = 0.f, accB = 0.f;
    #pragma unroll 8
    for (int ch = 0; ch < NCH; ++ch) {
        float xv = xrow[ch * LL];
        accA += xv * W0[ch * NF + k];
        accB += xv * W0[(NCH + ch) * NF + k];
    }
    Ap[gid] = (_Float16)(accA + b0[k]);
    Bp[gid] = (_Float16)accB;
}

// ---------------- phase 1: fused pair loop (all-fp16 operand path) ----------------
// grid: 2048 blocks (XCD-swizzled), 256 threads (4 waves); wave owns ONE p.
// phi (4-blocks 1<->2, 5<->6 of the hidden dim) folded into the W2 A-fragment load
// so layer-1 C/D registers feed layer-2's B-operand with no cross-lane ops (verified r3).
__global__ __launch_bounds__(256) void rn_main(
    const _Float16* __restrict__ Ap, const _Float16* __restrict__ Bp,
    const float* __restrict__ W1, const float* __restrict__ b1,
    const float* __restrict__ W2, const float* __restrict__ b2,
    float* __restrict__ partials)
{
    const int tid  = threadIdx.x;
    const int lane = tid & 63;
    const int w    = tid >> 6;
    const int col  = lane & 31;     // MFMA column index
    const int hi   = lane >> 5;     // half-wave
    // bijective XCD-contiguous swizzle (2048 % 8 == 0): each XCD gets 256 consecutive bids
    const int bid  = (blockIdx.x & 7) * 256 + (blockIdx.x >> 3);
    const int batch  = bid >> 6;
    const int pgroup = bid & 63;
    const int p      = pgroup * 4 + w;

    // ---- constant A-operand fragments (one-time cost) ----
    // A1 slot(kh,hi,e) = W1[k][col], k = 16kh+8hi+e ; A2 slot = W2[phi(k)][col]
    f16x8 a1[2], a2[2];
    #pragma unroll
    for (int kh = 0; kh < 2; ++kh) {
        #pragma unroll
        for (int e = 0; e < 8; ++e) {
            int k  = kh * 16 + 8 * hi + e;
            int bk = (k >> 2) & 3;
            int fk = (bk == 1 || bk == 2) ? (k ^ 12) : k;   // phi
            a1[kh][e] = (_Float16)W1[k  * NF + col];
            a2[kh][e] = (_Float16)W2[fk * NF + col];
        }
    }

    // ---- biases in the C/D register layout: row = (r&3)+8*(r>>2)+4*hi ----
    f32x16 bias1, bias2, sacc;
    #pragma unroll
    for (int r = 0; r < 16; ++r) {
        int row = (r & 3) + 8 * (r >> 2) + 4 * hi;
        bias1[r] = b1[row];
        bias2[r] = b2[row];
        sacc[r]  = 0.f;
    }

    // ---- B[p] slots (loaded once, fp16, already in fragment order) ----
    const _Float16* Brow = Bp + (batch * LL + p) * NF + 8 * hi;
    const f16x8 bq0 = *(const f16x8*)(Brow);        // k = 8hi + 0..7
    const f16x8 bq1 = *(const f16x8*)(Brow + 16);   // k = 16 + 8hi + 0..7

    const _Float16* Abase = Ap + batch * LL * NF + 8 * hi;
    const f16x8 z8 = {};

    #pragma unroll 2
    for (int q0 = 0; q0 < LL; q0 += 32) {
        const _Float16* Arow = Abase + (q0 + col) * NF;
        f16x8 t0 = *(const f16x8*)(Arow);
        f16x8 t1 = *(const f16x8*)(Arow + 16);

        // h1 = relu(A'[q] + B[p]) in fp16 -> directly the MFMA B-operand fragments
        f16x8 h0 = __builtin_elementwise_max(t0 + bq0, z8);
        f16x8 h1 = __builtin_elementwise_max(t1 + bq1, z8);

        // layer 1: h2pre^T = W1^T . h1^T + b1 (bias as C-input)
        f32x16 acc1 = __builtin_amdgcn_mfma_f32_32x32x16_f16(a1[0], h0, bias1, 0, 0, 0);
        acc1        = __builtin_amdgcn_mfma_f32_32x32x16_f16(a1[1], h1, acc1, 0, 0, 0);

        // relu + HW pack-convert (v_cvt_pkrtz_f16_f32, 1 op / 2 elems)
        f32x16 r1 = __builtin_elementwise_max(acc1, (f32x16)0.0f);
        f16x8 h2f0 = words_to_frag(pkrtz(r1[0],  r1[1]),  pkrtz(r1[2],  r1[3]),
                                   pkrtz(r1[4],  r1[5]),  pkrtz(r1[6],  r1[7]));
        f16x8 h2f1 = words_to_frag(pkrtz(r1[8],  r1[9]),  pkrtz(r1[10], r1[11]),
                                   pkrtz(r1[12], r1[13]), pkrtz(r1[14], r1[15]));

        // layer 2: h3pre^T = W2~^T . h2~^T + b2
        f32x16 acc2 = __builtin_amdgcn_mfma_f32_32x32x16_f16(a2[0], h2f0, bias2, 0, 0, 0);
        acc2        = __builtin_amdgcn_mfma_f32_32x32x16_f16(a2[1], h2f1, acc2, 0, 0, 0);

        // accumulate relu(h3)
        sacc += __builtin_elementwise_max(acc2, (f32x16)0.0f);
    }

    // ---- reduce: sum over pair-columns (lanes within each 32-half), then over waves ----
    float red[16];
    #pragma unroll
    for (int r = 0; r < 16; ++r) {
        float v = sacc[r];
        #pragma unroll
        for (int m = 1; m < 32; m <<= 1) v += __shfl_xor(v, m, 32);
        red[r] = v;
    }
    __shared__ float smem[4][32];
    if (col == 0) {
        #pragma unroll
        for (int r = 0; r < 16; ++r)
            smem[w][(r & 3) + 8 * (r >> 2) + 4 * hi] = red[r];
    }
    __syncthreads();
    if (tid < 32) {
        float s = smem[0][tid] + smem[1][tid] + smem[2][tid] + smem[3][tid];
        partials[bid * 32 + tid] = s;   // swizzled id keeps batch grouping for rn_post
    }
}

// ---------------- phase 2: reduce partials + MLP head ----------------
__global__ __launch_bounds__(1024) void rn_post(
    const float* __restrict__ partials,
    const float* __restrict__ Wp, const float* __restrict__ bp,
    const float* __restrict__ Wo, const float* __restrict__ bo,
    float* __restrict__ out)
{
    __shared__ float s_lds[32][32];
    __shared__ float f_lds[32][32];
    int tid = threadIdx.x;
    int b = tid >> 5, n = tid & 31;
    float s = 0.f;
    #pragma unroll 8
    for (int pb = 0; pb < 64; ++pb) s += partials[(b * 64 + pb) * 32 + n];
    s_lds[b][n] = s;
    __syncthreads();
    float f = bp[n];
    #pragma unroll
    for (int k = 0; k < 32; ++k) f += s_lds[b][k] * Wp[k * 32 + n];
    f_lds[b][n] = fmaxf(f, 0.f);
    __syncthreads();
    float o = bo[n];
    #pragma unroll
    for (int k = 0; k < 32; ++k) o += f_lds[b][k] * Wo[k * 32 + n];
    out[tid] = o;
}

extern "C" void kernel_launch(void* const* d_in, const int* in_sizes, int n_in,
                              void* d_out, int out_size, void* d_ws, size_t ws_size,
                              hipStream_t stream)
{
    const float* x  = (const float*)d_in[0];
    const float* W0 = (const float*)d_in[1];
    const float* b0 = (const float*)d_in[2];
    const float* W1 = (const float*)d_in[3];
    const float* b1 = (const float*)d_in[4];
    const float* W2 = (const float*)d_in[5];
    const float* b2 = (const float*)d_in[6];
    const float* Wp = (const float*)d_in[7];
    const float* bp = (const float*)d_in[8];
    const float* Wo = (const float*)d_in[9];
    const float* bo = (const float*)d_in[10];
    float* out = (float*)d_out;

    _Float16* Ap    = (_Float16*)d_ws;          // 262144 halves (512 KB)
    _Float16* Bp    = Ap + 32 * LL * NF;        // 262144 halves (512 KB)
    float* partials = (float*)(Bp + 32 * LL * NF);  // 2048*32 f32 (256 KB)

    rn_pre <<<1024, 256, 0, stream>>>(x, W0, b0, Ap, Bp);
    rn_main<<<2048, 256, 0, stream>>>(Ap, Bp, W1, b1, W2, b2, partials);
    rn_post<<<1, 1024, 0, stream>>>(partials, Wp, bp, Wo, bo, out);
}

// Round 6
// 34.197 us; speedup vs baseline: 1.6251x; 1.1548x over previous
//
#include <hip/hip_runtime.h>
#include <hip/hip_bf16.h>

typedef float    f32x4  __attribute__((ext_vector_type(4)));
typedef float    f32x16 __attribute__((ext_vector_type(16)));
typedef int      i32x4  __attribute__((ext_vector_type(4)));
typedef _Float16 f16x8  __attribute__((ext_vector_type(8)));

#define LL 256   // h*w
#define NF 32    // hidden dim
#define NCH 64   // channels

// HW pack: two f32 -> u32 of two fp16 (v_cvt_pkrtz_f16_f32)
__device__ __forceinline__ unsigned pkrtz(float lo, float hi) {
    return __builtin_bit_cast(unsigned, __builtin_amdgcn_cvt_pkrtz(lo, hi));
}

__device__ __forceinline__ f16x8 words_to_frag(unsigned w0, unsigned w1, unsigned w2, unsigned w3) {
    i32x4 w;
    w.x = (int)w0; w.y = (int)w1; w.z = (int)w2; w.w = (int)w3;
    return __builtin_bit_cast(f16x8, w);
}

// ---------------- phase 0: A'[b,l,k] = o @ W0[:64] + b0 (fp16) ; B[b,l,k] = o @ W0[64:] (fp16) ----
__global__ __launch_bounds__(256) void rn_pre(
    const float* __restrict__ x, const float* __restrict__ W0,
    const float* __restrict__ b0, _Float16* __restrict__ Ap, _Float16* __restrict__ Bp)
{
    int gid = blockIdx.x * 256 + threadIdx.x;   // 32*256*32 = 262144 threads
    int k  = gid & 31;
    int bl = gid >> 5;          // b*256 + l
    int b  = bl >> 8;
    int l  = bl & 255;
    const float* xrow = x + b * NCH * LL + l;   // x[b][ch][l]
    float accA = 0.f, accB = 0.f;
    #pragma unroll 8
    for (int ch = 0; ch < NCH; ++ch) {
        float xv = xrow[ch * LL];
        accA += xv * W0[ch * NF + k];
        accB += xv * W0[(NCH + ch) * NF + k];
    }
    Ap[gid] = (_Float16)(accA + b0[k]);
    Bp[gid] = (_Float16)accB;
}

// ---------------- phase 1: fused pair loop, 4-way ILP ----------------
// grid: 2048 blocks (XCD-swizzled) = 32 batches x 16 pgroups x 4 qchunks; 256 threads (4 waves).
// Each wave owns 4 consecutive p's and 2 q-tiles; the 4 p-chains share the A'-tile load and
// accumulate into ONE sacc (final result sums over p anyway). phi (hidden-dim 4-blocks
// 1<->2, 5<->6) folded into the W2 A-fragment so layer1 C/D feeds layer2 B directly (r3-verified).
__global__ __launch_bounds__(256) void rn_main(
    const _Float16* __restrict__ Ap, const _Float16* __restrict__ Bp,
    const float* __restrict__ W1, const float* __restrict__ b1,
    const float* __restrict__ W2, const float* __restrict__ b2,
    float* __restrict__ partials)
{
    const int tid  = threadIdx.x;
    const int lane = tid & 63;
    const int w    = tid >> 6;
    const int col  = lane & 31;     // MFMA column index
    const int hi   = lane >> 5;     // half-wave
    // bijective XCD-contiguous swizzle (2048 % 8 == 0)
    const int bid  = (blockIdx.x & 7) * 256 + (blockIdx.x >> 3);
    const int batch  = bid >> 6;
    const int rem    = bid & 63;
    const int pgroup = rem >> 2;    // 0..15
    const int qchunk = rem & 3;     // 0..3
    const int pbase  = pgroup * 16 + w * 4;
    const int q0base = qchunk * 64;

    // ---- constant A-operand fragments ----
    // A1 slot(kh,hi,e) = W1[k][col], k = 16kh+8hi+e ; A2 slot = W2[phi(k)][col]
    f16x8 a1[2], a2[2];
    #pragma unroll
    for (int kh = 0; kh < 2; ++kh) {
        #pragma unroll
        for (int e = 0; e < 8; ++e) {
            int k  = kh * 16 + 8 * hi + e;
            int bk = (k >> 2) & 3;
            int fk = (bk == 1 || bk == 2) ? (k ^ 12) : k;   // phi
            a1[kh][e] = (_Float16)W1[k  * NF + col];
            a2[kh][e] = (_Float16)W2[fk * NF + col];
        }
    }

    // ---- biases in the C/D register layout: row = (r&3)+8*(r>>2)+4*hi ----
    f32x16 bias1, bias2, sacc;
    #pragma unroll
    for (int r = 0; r < 16; ++r) {
        int row = (r & 3) + 8 * (r >> 2) + 4 * hi;
        bias1[r] = b1[row];
        bias2[r] = b2[row];
        sacc[r]  = 0.f;
    }

    // ---- B rows for the wave's 4 p's (fragment order) ----
    f16x8 bq0[4], bq1[4];
    #pragma unroll
    for (int i = 0; i < 4; ++i) {
        const _Float16* Brow = Bp + (batch * LL + pbase + i) * NF + 8 * hi;
        bq0[i] = *(const f16x8*)(Brow);        // k = 8hi + 0..7
        bq1[i] = *(const f16x8*)(Brow + 16);   // k = 16 + 8hi + 0..7
    }

    const _Float16* Abase = Ap + batch * LL * NF + 8 * hi;
    const f16x8 z8 = {};

    #pragma unroll
    for (int t = 0; t < 2; ++t) {
        const _Float16* Arow = Abase + (q0base + t * 32 + col) * NF;
        f16x8 t0 = *(const f16x8*)(Arow);
        f16x8 t1 = *(const f16x8*)(Arow + 16);

        #pragma unroll
        for (int i = 0; i < 4; ++i) {
            // h1 = relu(A'[q] + B[p_i]) in fp16 -> MFMA B-operand fragments directly
            f16x8 h0 = __builtin_elementwise_max(t0 + bq0[i], z8);
            f16x8 h1 = __builtin_elementwise_max(t1 + bq1[i], z8);

            // layer 1 (bias as C-input)
            f32x16 acc1 = __builtin_amdgcn_mfma_f32_32x32x16_f16(a1[0], h0, bias1, 0, 0, 0);
            acc1        = __builtin_amdgcn_mfma_f32_32x32x16_f16(a1[1], h1, acc1, 0, 0, 0);

            // relu + HW pack-convert
            f32x16 r1 = __builtin_elementwise_max(acc1, (f32x16)0.0f);
            f16x8 h2f0 = words_to_frag(pkrtz(r1[0],  r1[1]),  pkrtz(r1[2],  r1[3]),
                                       pkrtz(r1[4],  r1[5]),  pkrtz(r1[6],  r1[7]));
            f16x8 h2f1 = words_to_frag(pkrtz(r1[8],  r1[9]),  pkrtz(r1[10], r1[11]),
                                       pkrtz(r1[12], r1[13]), pkrtz(r1[14], r1[15]));

            // layer 2
            f32x16 acc2 = __builtin_amdgcn_mfma_f32_32x32x16_f16(a2[0], h2f0, bias2, 0, 0, 0);
            acc2        = __builtin_amdgcn_mfma_f32_32x32x16_f16(a2[1], h2f1, acc2, 0, 0, 0);

            // shared accumulation of relu(h3) across all 4 p-chains
            sacc += __builtin_elementwise_max(acc2, (f32x16)0.0f);
        }
    }

    // ---- reduce: sum over pair-columns (lanes within each 32-half), then over waves ----
    float red[16];
    #pragma unroll
    for (int r = 0; r < 16; ++r) {
        float v = sacc[r];
        #pragma unroll
        for (int m = 1; m < 32; m <<= 1) v += __shfl_xor(v, m, 32);
        red[r] = v;
    }
    __shared__ float smem[4][32];
    if (col == 0) {
        #pragma unroll
        for (int r = 0; r < 16; ++r)
            smem[w][(r & 3) + 8 * (r >> 2) + 4 * hi] = red[r];
    }
    __syncthreads();
    if (tid < 32) {
        float s = smem[0][tid] + smem[1][tid] + smem[2][tid] + smem[3][tid];
        partials[bid * 32 + tid] = s;   // bid = batch*64 + rem : contiguous per batch
    }
}

// ---------------- phase 2: per-batch reduce + MLP head (32 blocks) ----------------
__global__ __launch_bounds__(256) void rn_post(
    const float* __restrict__ partials,
    const float* __restrict__ Wp, const float* __restrict__ bp,
    const float* __restrict__ Wo, const float* __restrict__ bo,
    float* __restrict__ out)
{
    const int b   = blockIdx.x;       // 32 blocks, one per batch
    const int tid = threadIdx.x;      // 256 threads
    const int grp = tid >> 5, n = tid & 31;
    __shared__ float red[8][32];
    float s = 0.f;
    #pragma unroll
    for (int j = 0; j < 8; ++j)
        s += partials[(b * 64 + grp * 8 + j) * 32 + n];
    red[grp][n] = s;
    __syncthreads();
    if (tid < 32) {
        float sv = 0.f;
        #pragma unroll
        for (int g = 0; g < 8; ++g) sv += red[g][tid];
        // head via shfl broadcast (no same-wave LDS RAW hazard)
        float f = bp[tid];
        #pragma unroll
        for (int k = 0; k < 32; ++k)
            f += __shfl(sv, k, 32) * Wp[k * 32 + tid];
        f = fmaxf(f, 0.f);
        float o = bo[tid];
        #pragma unroll
        for (int k = 0; k < 32; ++k)
            o += __shfl(f, k, 32) * Wo[k * 32 + tid];
        out[b * 32 + tid] = o;
    }
}

extern "C" void kernel_launch(void* const* d_in, const int* in_sizes, int n_in,
                              void* d_out, int out_size, void* d_ws, size_t ws_size,
                              hipStream_t stream)
{
    const float* x  = (const float*)d_in[0];
    const float* W0 = (const float*)d_in[1];
    const float* b0 = (const float*)d_in[2];
    const float* W1 = (const float*)d_in[3];
    const float* b1 = (const float*)d_in[4];
    const float* W2 = (const float*)d_in[5];
    const float* b2 = (const float*)d_in[6];
    const float* Wp = (const float*)d_in[7];
    const float* bp = (const float*)d_in[8];
    const float* Wo = (const float*)d_in[9];
    const float* bo = (const float*)d_in[10];
    float* out = (float*)d_out;

    _Float16* Ap    = (_Float16*)d_ws;              // 262144 halves (512 KB)
    _Float16* Bp    = Ap + 32 * LL * NF;            // 262144 halves (512 KB)
    float* partials = (float*)(Bp + 32 * LL * NF);  // 2048*32 f32 (256 KB)

    rn_pre <<<1024, 256, 0, stream>>>(x, W0, b0, Ap, Bp);
    rn_main<<<2048, 256, 0, stream>>>(Ap, Bp, W1, b1, W2, b2, partials);
    rn_post<<<32, 256, 0, stream>>>(partials, Wp, bp, Wo, bo, out);
}